// Round 7
// baseline (377.339 us; speedup 1.0000x reference)
//
#include <hip/hip_runtime.h>

// Problem constants: B=4, S=4096, D=1024, H=64
#define NS 4       // attention key-range splits

typedef __attribute__((ext_vector_type(8))) short sh8;  // 8 x bf16 (4 VGPRs)
typedef __attribute__((ext_vector_type(4))) short sh4;  // 4 x bf16 (8 B)
typedef __attribute__((ext_vector_type(4))) float f4;   // MFMA accumulator

// fold 1/sqrt(64) * log2(e) into Q so softmax is pure exp2
#define QSCALE 0.18033688011112042f

static __device__ __forceinline__ unsigned short f2bf(float f) {
  unsigned u = __builtin_bit_cast(unsigned, f);
  u += 0x7fffu + ((u >> 16) & 1u);   // RNE
  return (unsigned short)(u >> 16);
}
static __device__ __forceinline__ float bf2f(unsigned short s) {
  unsigned u = ((unsigned)s) << 16;
  return __builtin_bit_cast(float, u);
}

// ---------------- kernel 1: Wt[192][1024] bf16 = concat(Wq,Wk,Wv)^T ----------------
__global__ __launch_bounds__(256) void wt_kernel(const float* __restrict__ Wq,
                                                 const float* __restrict__ Wk,
                                                 const float* __restrict__ Wv,
                                                 unsigned short* __restrict__ Wt) {
  __shared__ float tile[64 * 65];
  int widx = blockIdx.x >> 4, kt = blockIdx.x & 15;
  const float* W = widx == 0 ? Wq : (widx == 1 ? Wk : Wv);
  int t = threadIdx.x;
  {
    int kl = t >> 2, seg = (t & 3) * 16;
    const float* src = W + (size_t)(kt * 64 + kl) * 64 + seg;
#pragma unroll
    for (int j = 0; j < 16; ++j) tile[kl * 65 + seg + j] = src[j];
  }
  __syncthreads();
  {
    int nl = t >> 2, ks = (t & 3) * 16;
    unsigned short* dst = Wt + (size_t)(widx * 64 + nl) * 1024 + kt * 64 + ks;
#pragma unroll
    for (int j = 0; j < 16; ++j) dst[j] = f2bf(tile[(ks + j) * 65 + nl]);
  }
}

// ---------------- kernel 2: barrier-free-loop projection, register-dbuf ----------------
// 1024 blocks x 256 threads. Block = m-tile (16 rows). Wave (nh,kh) = n-half (96) x k-half (512).
// A and B fragments loaded straight from global in MFMA layout, double-buffered in VGPRs
// (1-iter lookahead). No LDS/barriers in the K-loop; one barrier for the 2-way k-reduce.
__global__ __launch_bounds__(256, 4) void proj_kernel(const float* __restrict__ in,
                                                      const unsigned short* __restrict__ Wt,
                                                      unsigned short* __restrict__ Qg,
                                                      unsigned short* __restrict__ Kg,
                                                      unsigned short* __restrict__ Vtg) {
  __shared__ float red[2][16][196];   // 25088 B: kh partials, pad 196
  __shared__ float vtile[16][68];     // 4352 B: V transpose staging
  int t = threadIdx.x;
  int wave = t >> 6, lane = t & 63, quad = lane >> 4, l15 = lane & 15;
  int nh = wave & 1, kh = wave >> 1;
  int m0 = blockIdx.x * 16;
  int k0 = kh * 512;

  const float* ga = in + (size_t)(m0 + l15) * 1024 + k0 + quad * 8;
  const unsigned short* gb = Wt + (size_t)(nh * 96 + l15) * 1024 + k0 + quad * 8;

  f4 acc[6];
  f4 z = {0.f, 0.f, 0.f, 0.f};
#pragma unroll
  for (int nt = 0; nt < 6; ++nt) acc[nt] = z;

  // register double buffers
  f4 alo[2], ahi[2];
  sh8 bf[2][6];
  alo[0] = *(const f4*)ga;
  ahi[0] = *(const f4*)(ga + 4);
#pragma unroll
  for (int nt = 0; nt < 6; ++nt) bf[0][nt] = *(const sh8*)(gb + (size_t)nt * 16384);

  for (int kk = 0; kk < 16; ++kk) {
    int cur = kk & 1, nxt = cur ^ 1;
    if (kk + 1 < 16) {  // issue next-iter loads first (1-iter lookahead)
      const float* pa = ga + (kk + 1) * 32;
      alo[nxt] = *(const f4*)pa;
      ahi[nxt] = *(const f4*)(pa + 4);
#pragma unroll
      for (int nt = 0; nt < 6; ++nt)
        bf[nxt][nt] = *(const sh8*)(gb + (size_t)nt * 16384 + (kk + 1) * 32);
    }
    sh8 af;
#pragma unroll
    for (int j = 0; j < 4; ++j) {
      af[j] = (short)f2bf(alo[cur][j]);
      af[4 + j] = (short)f2bf(ahi[cur][j]);
    }
#pragma unroll
    for (int nt = 0; nt < 6; ++nt)
      acc[nt] = __builtin_amdgcn_mfma_f32_16x16x32_bf16(af, bf[cur][nt], acc[nt], 0, 0, 0);
  }

  // dump partials (C-layout: row = quad*4+r, col = nh*96 + nt*16 + l15)
#pragma unroll
  for (int nt = 0; nt < 6; ++nt)
#pragma unroll
    for (int r = 0; r < 4; ++r)
      red[kh][quad * 4 + r][nh * 96 + nt * 16 + l15] = acc[nt][r];
  __syncthreads();

  // k-reduce + band split: thread row = t>>4, 12 cols at (t&15)*12
  {
    int row = t >> 4, cb = (t & 15) * 12;
#pragma unroll
    for (int j = 0; j < 12; ++j) {
      int c = cb + j;
      float v = red[0][row][c] + red[1][row][c];
      if (c < 64)       Qg[(size_t)(m0 + row) * 64 + c] = f2bf(v * QSCALE);
      else if (c < 128) Kg[(size_t)(m0 + row) * 64 + (c - 64)] = f2bf(v);
      else              vtile[row][c - 128] = v;
    }
  }
  __syncthreads();
  {  // V transposed out
    int h = t >> 2, sl = (t & 3) * 4;
    int bb = m0 >> 12, s0 = m0 & 4095;
    sh4 vv;
#pragma unroll
    for (int j = 0; j < 4; ++j) vv[j] = (short)f2bf(vtile[sl + j][h]);
    *(sh4*)&Vtg[(((size_t)(bb * 64 + h)) << 12) + s0 + sl] = vv;
  }
}

// ---------------- kernel 3: causal flash attention + fused split combine ----------------
// grid (64*NS, B), 256 threads (4 waves). Block = q-tile of 64 rows x key-chunk.
// Last block of each (b,qt) group combines the NS partials (threadfence + atomic counter).
__global__ __launch_bounds__(256, 4) void attn_split(const unsigned short* __restrict__ Qg,
                                                     const unsigned short* __restrict__ Kg,
                                                     const unsigned short* __restrict__ Vtg,
                                                     unsigned short* __restrict__ Opart,
                                                     float* __restrict__ Lpart,
                                                     int* __restrict__ cnt,
                                                     float* __restrict__ out) {
  __shared__ unsigned short Ks[64 * 72];
  __shared__ unsigned short Vs[64 * 72];
  __shared__ unsigned short Pw[4 * 16 * 72];
  __shared__ int lastflag;
  int t = threadIdx.x;
  int b = blockIdx.y;
  int qt = 63 - (int)(blockIdx.x >> 2);  // heavy q-tiles first (LPT)
  int sp = blockIdx.x & 3;
  int wave = t >> 6, lane = t & 63, quad = lane >> 4, l15 = lane & 15;
  unsigned short* Pws = Pw + wave * 16 * 72;

  int qrow0 = qt * 64 + wave * 16;
  size_t pbase = ((size_t)sp * 4 + b) * 4096;

  int nkt = qt + 1;
  int chunk = (nkt + NS - 1) / NS;
  int t0 = sp * chunk, t1 = min(nkt, t0 + chunk);

  if (t0 >= t1) {  // empty chunk: zero partials (still participates in combine protocol)
#pragma unroll
    for (int r = 0; r < 4; ++r) {
      size_t row = pbase + qrow0 + quad * 4 + r;
#pragma unroll
      for (int ht = 0; ht < 4; ++ht) Opart[row * 64 + ht * 16 + l15] = 0;
      if (l15 == 0) Lpart[row] = 0.f;
    }
  } else {
    sh8 qa[2];
#pragma unroll
    for (int ks = 0; ks < 2; ++ks)
      qa[ks] = *(const sh8*)&Qg[(size_t)((b << 12) + qrow0 + l15) * 64 + ks * 32 + quad * 8];

    sh8 ones;
#pragma unroll
    for (int j = 0; j < 8; ++j) ones[j] = (short)0x3F80;  // bf16 1.0

    f4 o[5];  // o[0..3]: O accumulator; o[4]: row-sum (P * ones)
    f4 z = {0.f, 0.f, 0.f, 0.f};
#pragma unroll
    for (int ht = 0; ht < 5; ++ht) o[ht] = z;

    // staging geometry: thread covers chunks c0=t, c1=t+256; row=c>>3, off=(c&7)*8
    int r0 = t >> 3, o0 = (t & 7) * 8;
    int r1 = (t + 256) >> 3, o1 = ((t + 256) & 7) * 8;
    const unsigned short* kg0 = Kg + (size_t)((b << 12) + r0) * 64 + o0;
    const unsigned short* kg1 = Kg + (size_t)((b << 12) + r1) * 64 + o1;
    const unsigned short* vg0 = Vtg + (((size_t)(b * 64 + r0)) << 12) + o0;
    const unsigned short* vg1 = Vtg + (((size_t)(b * 64 + r1)) << 12) + o1;

    sh8 kr0, kr1, vr0, vr1;
    {
      size_t ko = (size_t)t0 * 64 * 64;
      kr0 = *(const sh8*)(kg0 + ko); kr1 = *(const sh8*)(kg1 + ko);
      vr0 = *(const sh8*)(vg0 + t0 * 64); vr1 = *(const sh8*)(vg1 + t0 * 64);
    }

    for (int kt = t0; kt < t1; ++kt) {
      __syncthreads();                      // prev-iter LDS reads done
      *(sh8*)&Ks[r0 * 72 + o0] = kr0;
      *(sh8*)&Ks[r1 * 72 + o1] = kr1;
      *(sh8*)&Vs[r0 * 72 + o0] = vr0;
      *(sh8*)&Vs[r1 * 72 + o1] = vr1;
      if (kt + 1 < t1) {                    // prefetch next tile into regs
        size_t ko = (size_t)(kt + 1) * 64 * 64;
        kr0 = *(const sh8*)(kg0 + ko); kr1 = *(const sh8*)(kg1 + ko);
        vr0 = *(const sh8*)(vg0 + (kt + 1) * 64); vr1 = *(const sh8*)(vg1 + (kt + 1) * 64);
      }
      __syncthreads();                      // Ks/Vs visible

      f4 s[4];
#pragma unroll
      for (int nt = 0; nt < 4; ++nt) s[nt] = z;
#pragma unroll
      for (int ks = 0; ks < 2; ++ks) {
#pragma unroll
        for (int nt = 0; nt < 4; ++nt) {
          sh8 kb = *(const sh8*)&Ks[(nt * 16 + l15) * 72 + ks * 32 + quad * 8];
          s[nt] = __builtin_amdgcn_mfma_f32_16x16x32_bf16(qa[ks], kb, s[nt], 0, 0, 0);
        }
      }

      if (kt == nkt - 1) {  // causal mask on the global diagonal tile
#pragma unroll
        for (int nt = 0; nt < 4; ++nt) {
          int key = kt * 64 + nt * 16 + l15;
#pragma unroll
          for (int r = 0; r < 4; ++r) {
            int row = qrow0 + quad * 4 + r;
            if (key > row) s[nt][r] = -__builtin_inff();
          }
        }
      }

      // static-max softmax: P = exp2(s); wave-private LDS round-trip (C->A layout)
#pragma unroll
      for (int nt = 0; nt < 4; ++nt)
#pragma unroll
        for (int r = 0; r < 4; ++r)
          Pws[(quad * 4 + r) * 72 + nt * 16 + l15] = f2bf(exp2f(s[nt][r]));
      asm volatile("s_waitcnt lgkmcnt(0)" ::: "memory");

#pragma unroll
      for (int ks = 0; ks < 2; ++ks) {
        sh8 pa = *(const sh8*)&Pws[l15 * 72 + ks * 32 + quad * 8];
#pragma unroll
        for (int ht = 0; ht < 4; ++ht) {
          sh8 vb = *(const sh8*)&Vs[(ht * 16 + l15) * 72 + ks * 32 + quad * 8];
          o[ht] = __builtin_amdgcn_mfma_f32_16x16x32_bf16(pa, vb, o[ht], 0, 0, 0);
        }
        o[4] = __builtin_amdgcn_mfma_f32_16x16x32_bf16(pa, ones, o[4], 0, 0, 0);
      }
    }

    // write partials (unnormalized O, bf16; L fp32)
#pragma unroll
    for (int r = 0; r < 4; ++r) {
      size_t row = pbase + qrow0 + quad * 4 + r;
#pragma unroll
      for (int ht = 0; ht < 4; ++ht)
        Opart[row * 64 + ht * 16 + l15] = f2bf(o[ht][r]);
      if (l15 == 0) Lpart[row] = o[4][r];
    }
  }

  // ----- last-block-done combine -----
  __threadfence();    // release: partials visible device-wide
  __syncthreads();    // all waves' stores issued+fenced
  if (t == 0) {
    int g = b * 64 + qt;
    int old = atomicAdd(&cnt[g], 1);
    lastflag = (old == NS - 1);
  }
  __syncthreads();
  if (lastflag) {
    __threadfence();  // acquire: see other blocks' partials
    int row = t >> 2, cb = (t & 3) * 16;   // 64 rows x 16 cols per thread
    size_t qrow = (size_t)qt * 64 + row;
    float accv[16];
#pragma unroll
    for (int j = 0; j < 16; ++j) accv[j] = 0.f;
    float L = 0.f;
#pragma unroll
    for (int s = 0; s < NS; ++s) {
      size_t prow = ((size_t)s * 4 + b) * 4096 + qrow;
      L += Lpart[prow];
      const unsigned short* po = Opart + prow * 64 + cb;
#pragma unroll
      for (int j = 0; j < 16; ++j) accv[j] += bf2f(po[j]);
    }
    float inv = 1.0f / L;
    float* po = out + ((size_t)(b << 12) + qrow) * 64 + cb;
#pragma unroll
    for (int j = 0; j < 16; ++j) po[j] = accv[j] * inv;
  }
}

extern "C" void kernel_launch(void* const* d_in, const int* in_sizes, int n_in,
                              void* d_out, int out_size, void* d_ws, size_t ws_size,
                              hipStream_t stream) {
  const float* in = (const float*)d_in[0];
  const float* Wq = (const float*)d_in[1];
  const float* Wk = (const float*)d_in[2];
  const float* Wv = (const float*)d_in[3];
  float* out = (float*)d_out;

  char* ws = (char*)d_ws;
  unsigned short* Wt    = (unsigned short*)ws;                 // 393,216 B
  unsigned short* Qg    = (unsigned short*)(ws + 393216);      // 2 MiB
  unsigned short* Kg    = (unsigned short*)(ws + 2490368);     // 2 MiB
  unsigned short* Vtg   = (unsigned short*)(ws + 4587520);     // 2 MiB
  unsigned short* Opart = (unsigned short*)(ws + 6684672);     // 8,388,608 B
  float*          Lpart = (float*)(ws + 15073280);             // 262,144 B
  int*            cnt   = (int*)(ws + 15335424);               // 1,024 B

  hipMemsetAsync(cnt, 0, 1024, stream);
  hipLaunchKernelGGL(wt_kernel, dim3(48), dim3(256), 0, stream, Wq, Wk, Wv, Wt);
  hipLaunchKernelGGL(proj_kernel, dim3(1024), dim3(256), 0, stream, in, Wt, Qg, Kg, Vtg);
  hipLaunchKernelGGL(attn_split, dim3(64 * NS, 4), dim3(256), 0, stream,
                     Qg, Kg, Vtg, Opart, Lpart, cnt, out);
}

// Round 8
// 159.441 us; speedup vs baseline: 2.3666x; 2.3666x over previous
//
#include <hip/hip_runtime.h>

// Problem constants: B=4, S=4096, D=1024, H=64
#define NS 8       // attention key-range splits

typedef __attribute__((ext_vector_type(8))) short sh8;  // 8 x bf16 (4 VGPRs)
typedef __attribute__((ext_vector_type(4))) short sh4;  // 4 x bf16 (8 B)
typedef __attribute__((ext_vector_type(4))) float f4;   // MFMA accumulator

// fold 1/sqrt(64) * log2(e) into Q so softmax is pure exp2
#define QSCALE 0.18033688011112042f

typedef const __attribute__((address_space(1))) unsigned int* gas_t;
typedef __attribute__((address_space(3))) unsigned int* las_t;
#define GLD16(g, l) __builtin_amdgcn_global_load_lds((gas_t)(g), (las_t)(l), 16, 0, 0)

static __device__ __forceinline__ unsigned short f2bf(float f) {
  unsigned u = __builtin_bit_cast(unsigned, f);
  u += 0x7fffu + ((u >> 16) & 1u);   // RNE
  return (unsigned short)(u >> 16);
}
static __device__ __forceinline__ float bf2f(unsigned short s) {
  unsigned u = ((unsigned)s) << 16;
  return __builtin_bit_cast(float, u);
}

// ---------------- kernel 1: Wt[192][1024] bf16 = concat(Wq,Wk,Wv)^T ----------------
__global__ __launch_bounds__(256) void wt_kernel(const float* __restrict__ Wq,
                                                 const float* __restrict__ Wk,
                                                 const float* __restrict__ Wv,
                                                 unsigned short* __restrict__ Wt) {
  __shared__ float tile[64 * 65];
  int widx = blockIdx.x >> 4, kt = blockIdx.x & 15;
  const float* W = widx == 0 ? Wq : (widx == 1 ? Wk : Wv);
  int t = threadIdx.x;
  {
    int kl = t >> 2, seg = (t & 3) * 16;
    const float* src = W + (size_t)(kt * 64 + kl) * 64 + seg;
#pragma unroll
    for (int j = 0; j < 16; ++j) tile[kl * 65 + seg + j] = src[j];
  }
  __syncthreads();
  {
    int nl = t >> 2, ks = (t & 3) * 16;
    unsigned short* dst = Wt + (size_t)(widx * 64 + nl) * 1024 + kt * 64 + ks;
#pragma unroll
    for (int j = 0; j < 16; ++j) dst[j] = f2bf(tile[(ks + j) * 65 + nl]);
  }
}

// ---------------- kernel 2: projection (R4 glds pipeline, measured 50 us) ----------------
// 512 blocks x 256 threads (4 waves). Block tile: M=32, N=192, k-step 32, 32 iters.
// LDS per buffer: A chunks [4][1KB] fp32 + B chunks [12][1KB] bf16 = 16 KB; double-buffered.
__global__ __launch_bounds__(256, 4) void proj_kernel(const float* __restrict__ in,
                                                      const unsigned short* __restrict__ Wt,
                                                      unsigned short* __restrict__ Qg,
                                                      unsigned short* __restrict__ Kg,
                                                      unsigned short* __restrict__ Vtg) {
  __shared__ __align__(16) char lds[32768];
  int t = threadIdx.x;
  int w = t >> 6, lane = t & 63, q = lane >> 4, l15 = lane & 15;
  int m0 = blockIdx.x * 32;

  int mt_s = w >> 1, i_s = w & 1;
  const float* ga = in + (size_t)(m0 + mt_s * 16 + l15) * 1024 + q * 8 + i_s * 4;
  const unsigned short* gb = Wt + (size_t)(w * 48 + l15) * 1024 + q * 8;

  f4 acc[2][3];
  f4 z = {0.f, 0.f, 0.f, 0.f};
#pragma unroll
  for (int mt = 0; mt < 2; ++mt)
#pragma unroll
    for (int nt = 0; nt < 3; ++nt) acc[mt][nt] = z;

#define STAGE(kt, buf)                                                        \
  {                                                                           \
    int k0 = (kt) * 32;                                                       \
    char* base = lds + (buf) * 16384;                                         \
    GLD16(ga + k0, base + w * 1024);                                          \
    GLD16(gb + k0, base + 4096 + (w * 3 + 0) * 1024);                         \
    GLD16(gb + 16384 + k0, base + 4096 + (w * 3 + 1) * 1024);                 \
    GLD16(gb + 32768 + k0, base + 4096 + (w * 3 + 2) * 1024);                 \
  }

  STAGE(0, 0);
  for (int kt = 0; kt < 32; ++kt) {
    int cur = kt & 1;
    __syncthreads();
    if (kt + 1 < 32) STAGE(kt + 1, cur ^ 1);

    const f4* Af = (const f4*)(lds + cur * 16384);
    f4 lo0 = Af[0 * 64 + lane], hi0 = Af[1 * 64 + lane];
    f4 lo1 = Af[2 * 64 + lane], hi1 = Af[3 * 64 + lane];
    sh8 a0, a1;
#pragma unroll
    for (int j = 0; j < 4; ++j) {
      a0[j] = (short)f2bf(lo0[j]); a0[4 + j] = (short)f2bf(hi0[j]);
      a1[j] = (short)f2bf(lo1[j]); a1[4 + j] = (short)f2bf(hi1[j]);
    }
    const sh8* Bf = (const sh8*)(lds + cur * 16384 + 4096);
#pragma unroll
    for (int nt = 0; nt < 3; ++nt) {
      sh8 bf = Bf[(w * 3 + nt) * 64 + lane];
      acc[0][nt] = __builtin_amdgcn_mfma_f32_16x16x32_bf16(a0, bf, acc[0][nt], 0, 0, 0);
      acc[1][nt] = __builtin_amdgcn_mfma_f32_16x16x32_bf16(a1, bf, acc[1][nt], 0, 0, 0);
    }
  }
#undef STAGE

  // epilogue: wave w owns cols w*48 + nt*16 + l15; bands: 0-3 Q, 4-7 K, 8-11 V
  float* vred = (float*)lds;   // [32][69] fp32 (aliases buf0; last compute read buf1)
#pragma unroll
  for (int nt = 0; nt < 3; ++nt) {
    int band = w * 3 + nt;
#pragma unroll
    for (int mt = 0; mt < 2; ++mt)
#pragma unroll
      for (int r = 0; r < 4; ++r) {
        int row = mt * 16 + q * 4 + r;
        float v = acc[mt][nt][r];
        if (band < 4) {
          Qg[(size_t)(m0 + row) * 64 + band * 16 + l15] = f2bf(v * QSCALE);
        } else if (band < 8) {
          Kg[(size_t)(m0 + row) * 64 + (band - 4) * 16 + l15] = f2bf(v);
        } else {
          vred[row * 69 + (band - 8) * 16 + l15] = v;
        }
      }
  }
  __syncthreads();
  {
    int h = t >> 2, sl = (t & 3) * 8;
    int bb = m0 >> 12, s0 = m0 & 4095;
    sh8 vv;
#pragma unroll
    for (int j = 0; j < 8; ++j) vv[j] = (short)f2bf(vred[(sl + j) * 69 + h]);
    *(sh8*)&Vtg[(((size_t)(bb * 64 + h)) << 12) + s0 + sl] = vv;
  }
}

// ---------------- kernel 3: causal flash attention, S^T trick, split-K ----------------
// grid (64*NS, B), 256 threads (4 waves). Block = q-tile of 64 rows x key-chunk.
// S^T = K*Q^T via operand swap: each lane holds 4 contiguous keys for one qrow,
// so the P round-trip writes are 4x b64 instead of 16x b16.
__global__ __launch_bounds__(256, 4) void attn_split(const unsigned short* __restrict__ Qg,
                                                     const unsigned short* __restrict__ Kg,
                                                     const unsigned short* __restrict__ Vtg,
                                                     unsigned short* __restrict__ Opart,
                                                     float* __restrict__ Lpart) {
  __shared__ unsigned short Ks[64 * 72];
  __shared__ unsigned short Vs[64 * 72];
  __shared__ unsigned short Pw[4 * 16 * 72];
  int t = threadIdx.x;
  int b = blockIdx.y;
  int qt = 63 - (int)(blockIdx.x >> 3);  // heavy q-tiles first (LPT)
  int sp = blockIdx.x & 7;
  int wave = t >> 6, lane = t & 63, quad = lane >> 4, l15 = lane & 15;
  unsigned short* Pws = Pw + wave * 16 * 72;

  int qrow0 = qt * 64 + wave * 16;
  size_t pbase = ((size_t)sp * 4 + b) * 4096;

  int nkt = qt + 1;
  int chunk = (nkt + NS - 1) / NS;
  int t0 = sp * chunk, t1 = min(nkt, t0 + chunk);
  if (t0 >= t1) {  // empty chunk: zero partials
#pragma unroll
    for (int r = 0; r < 4; ++r) {
      size_t row = pbase + qrow0 + quad * 4 + r;
#pragma unroll
      for (int ht = 0; ht < 4; ++ht) Opart[row * 64 + ht * 16 + l15] = 0;
      if (l15 == 0) Lpart[row] = 0.f;
    }
    return;
  }

  sh8 qa[2];
#pragma unroll
  for (int ks = 0; ks < 2; ++ks)
    qa[ks] = *(const sh8*)&Qg[(size_t)((b << 12) + qrow0 + l15) * 64 + ks * 32 + quad * 8];

  sh8 ones;
#pragma unroll
  for (int j = 0; j < 8; ++j) ones[j] = (short)0x3F80;  // bf16 1.0

  f4 o[5];  // o[0..3]: O accumulator; o[4]: row-sum (P * ones)
  f4 z = {0.f, 0.f, 0.f, 0.f};
#pragma unroll
  for (int ht = 0; ht < 5; ++ht) o[ht] = z;

  // staging geometry: thread covers chunks c0=t, c1=t+256; row=c>>3, off=(c&7)*8
  int r0 = t >> 3, o0 = (t & 7) * 8;
  int r1 = (t + 256) >> 3, o1 = ((t + 256) & 7) * 8;
  const unsigned short* kg0 = Kg + (size_t)((b << 12) + r0) * 64 + o0;
  const unsigned short* kg1 = Kg + (size_t)((b << 12) + r1) * 64 + o1;
  const unsigned short* vg0 = Vtg + (((size_t)(b * 64 + r0)) << 12) + o0;
  const unsigned short* vg1 = Vtg + (((size_t)(b * 64 + r1)) << 12) + o1;

  sh8 kr0, kr1, vr0, vr1;
  {
    size_t ko = (size_t)t0 * 64 * 64;
    kr0 = *(const sh8*)(kg0 + ko); kr1 = *(const sh8*)(kg1 + ko);
    vr0 = *(const sh8*)(vg0 + t0 * 64); vr1 = *(const sh8*)(vg1 + t0 * 64);
  }

  for (int kt = t0; kt < t1; ++kt) {
    __syncthreads();                      // prev-iter LDS reads done
    *(sh8*)&Ks[r0 * 72 + o0] = kr0;
    *(sh8*)&Ks[r1 * 72 + o1] = kr1;
    *(sh8*)&Vs[r0 * 72 + o0] = vr0;
    *(sh8*)&Vs[r1 * 72 + o1] = vr1;
    if (kt + 1 < t1) {                    // prefetch next tile into regs
      size_t ko = (size_t)(kt + 1) * 64 * 64;
      kr0 = *(const sh8*)(kg0 + ko); kr1 = *(const sh8*)(kg1 + ko);
      vr0 = *(const sh8*)(vg0 + (kt + 1) * 64); vr1 = *(const sh8*)(vg1 + (kt + 1) * 64);
    }
    __syncthreads();                      // Ks/Vs visible

    // S^T = K * Q^T: st[nt] lane(quad,l15) reg r = S[qrow0+l15][kt*64+nt*16+quad*4+r]
    f4 st[4];
#pragma unroll
    for (int nt = 0; nt < 4; ++nt) st[nt] = z;
#pragma unroll
    for (int ks = 0; ks < 2; ++ks) {
#pragma unroll
      for (int nt = 0; nt < 4; ++nt) {
        sh8 kb = *(const sh8*)&Ks[(nt * 16 + l15) * 72 + ks * 32 + quad * 8];
        st[nt] = __builtin_amdgcn_mfma_f32_16x16x32_bf16(kb, qa[ks], st[nt], 0, 0, 0);
      }
    }

    if (kt == nkt - 1) {  // causal mask on the global diagonal tile
      int qrow = qrow0 + l15;
#pragma unroll
      for (int nt = 0; nt < 4; ++nt) {
        int key0 = kt * 64 + nt * 16 + quad * 4;
#pragma unroll
        for (int r = 0; r < 4; ++r)
          if (key0 + r > qrow) st[nt][r] = -__builtin_inff();
      }
    }

    // static-max softmax: P = exp2(S); pack 4 contiguous keys -> one b64 LDS write
#pragma unroll
    for (int nt = 0; nt < 4; ++nt) {
      sh4 pk;
#pragma unroll
      for (int r = 0; r < 4; ++r) pk[r] = (short)f2bf(exp2f(st[nt][r]));
      *(sh4*)&Pws[l15 * 72 + nt * 16 + quad * 4] = pk;
    }
    asm volatile("s_waitcnt lgkmcnt(0)" ::: "memory");

#pragma unroll
    for (int ks = 0; ks < 2; ++ks) {
      sh8 pa = *(const sh8*)&Pws[l15 * 72 + ks * 32 + quad * 8];
#pragma unroll
      for (int ht = 0; ht < 4; ++ht) {
        sh8 vb = *(const sh8*)&Vs[(ht * 16 + l15) * 72 + ks * 32 + quad * 8];
        o[ht] = __builtin_amdgcn_mfma_f32_16x16x32_bf16(pa, vb, o[ht], 0, 0, 0);
      }
      o[4] = __builtin_amdgcn_mfma_f32_16x16x32_bf16(pa, ones, o[4], 0, 0, 0);
    }
  }

  // write partials (unnormalized O, bf16; L fp32)
#pragma unroll
  for (int r = 0; r < 4; ++r) {
    size_t row = pbase + qrow0 + quad * 4 + r;
#pragma unroll
    for (int ht = 0; ht < 4; ++ht)
      Opart[row * 64 + ht * 16 + l15] = f2bf(o[ht][r]);
    if (l15 == 0) Lpart[row] = o[4][r];
  }
}

// ---------------- kernel 4: combine split partials ----------------
__global__ __launch_bounds__(256) void attn_combine(const unsigned short* __restrict__ Opart,
                                                    const float* __restrict__ Lpart,
                                                    float* __restrict__ out) {
  int t = threadIdx.x;
  int rg = blockIdx.x * 4 + (t >> 6);  // global row 0..16383
  int lane = t & 63;
  float acc = 0.f, L = 0.f;
#pragma unroll
  for (int s = 0; s < NS; ++s) {
    L += Lpart[(size_t)s * 16384 + rg];
    acc += bf2f(Opart[((size_t)s * 16384 + rg) * 64 + lane]);
  }
  out[(size_t)rg * 64 + lane] = acc / L;
}

extern "C" void kernel_launch(void* const* d_in, const int* in_sizes, int n_in,
                              void* d_out, int out_size, void* d_ws, size_t ws_size,
                              hipStream_t stream) {
  const float* in = (const float*)d_in[0];
  const float* Wq = (const float*)d_in[1];
  const float* Wk = (const float*)d_in[2];
  const float* Wv = (const float*)d_in[3];
  float* out = (float*)d_out;

  char* ws = (char*)d_ws;
  unsigned short* Wt    = (unsigned short*)ws;                 // 393,216 B
  unsigned short* Qg    = (unsigned short*)(ws + 393216);      // 2 MiB
  unsigned short* Kg    = (unsigned short*)(ws + 2490368);     // 2 MiB
  unsigned short* Vtg   = (unsigned short*)(ws + 4587520);     // 2 MiB
  unsigned short* Opart = (unsigned short*)(ws + 6684672);     // 16,777,216 B
  float*          Lpart = (float*)(ws + 23461888);             // 524,288 B
  // total ws use ~24 MiB

  hipLaunchKernelGGL(wt_kernel, dim3(48), dim3(256), 0, stream, Wq, Wk, Wv, Wt);
  hipLaunchKernelGGL(proj_kernel, dim3(512), dim3(256), 0, stream, in, Wt, Qg, Kg, Vtg);
  hipLaunchKernelGGL(attn_split, dim3(64 * NS, 4), dim3(256), 0, stream,
                     Qg, Kg, Vtg, Opart, Lpart);
  hipLaunchKernelGGL(attn_combine, dim3(4096), dim3(256), 0, stream,
                     Opart, Lpart, out);
}